// Round 1
// baseline (842.286 us; speedup 1.0000x reference)
//
#include <hip/hip_runtime.h>
#include <math.h>

#define PCH 256
#define HD  1024
#define BB  8
#define LL  4096
#define NN  512                  // 2*P
#define MROWS (BB*LL)            // 32768
#define NCH 64                   // number of chunks
#define TCH 64                   // chunk length (NCH*TCH == LL)

// ---- workspace layout (float offsets) ----
#define OFF_W1     ((size_t)0)
#define OFF_C2     (OFF_W1 + (size_t)HD*NN)
#define OFF_CONSTS (OFF_C2 + (size_t)NN*HD)
#define OFF_BU     (OFF_CONSTS + (size_t)16*PCH)
#define OFF_YS     (OFF_BU + (size_t)MROWS*NN)
#define OFF_ZEND   (OFF_YS + (size_t)MROWS*NN)
#define OFF_CARRY  (OFF_ZEND + (size_t)BB*NCH*2*NN)
#define WS_FLOATS  (OFF_CARRY + (size_t)BB*NCH*2*NN)

// consts layout: j*PCH + p ; j: 0=m11 1=m12 2=m21 3=m22 4=c1 5=c2 6=mt11 7=mt12 8=mt21 9=mt22
__global__ void prep_consts(const float* __restrict__ steps_raw,
                            const float* __restrict__ G_raw,
                            const float* __restrict__ A_raw,
                            float* __restrict__ cst) {
    int p = threadIdx.x;
    if (p >= PCH) return;
    float steps = 1.0f / (1.0f + expf(-steps_raw[p]));
    float G = fmaxf(G_raw[p], 0.0f);
    float A = fmaxf(A_raw[p], 0.0f);
    float S = 1.0f + steps * G;
    float alpha = steps * steps * A / S;
    alpha = 1.99f * tanhf(alpha / 1.99f);
    float m11 = 1.0f / S;
    float m12 = -alpha / steps;
    float m21 = steps / S;
    float m22 = 1.0f - alpha;
    float c1 = steps / S;            // F1 = c1 * Bu
    float c2 = steps * steps / S;    // F2 = c2 * Bu
    // M^TCH by repeated left-multiply
    float a = 1.f, b = 0.f, c = 0.f, d = 1.f;
    for (int i = 0; i < TCH; ++i) {
        float na = m11*a + m12*c;
        float nb = m11*b + m12*d;
        float nc = m21*a + m22*c;
        float nd = m21*b + m22*d;
        a = na; b = nb; c = nc; d = nd;
    }
    cst[0*PCH+p] = m11; cst[1*PCH+p] = m12; cst[2*PCH+p] = m21; cst[3*PCH+p] = m22;
    cst[4*PCH+p] = c1;  cst[5*PCH+p] = c2;
    cst[6*PCH+p] = a;   cst[7*PCH+p] = b;   cst[8*PCH+p] = c;   cst[9*PCH+p] = d;
}

// Build W1[h][n] = B_mat[p][h][t], C2[n][h] = sign(t) * C_mat[h][p][t]; n = 2p+t
__global__ void prep_w(const float* __restrict__ B_mat,
                       const float* __restrict__ C_mat,
                       float* __restrict__ W1,
                       float* __restrict__ C2) {
    int idx = blockIdx.x * blockDim.x + threadIdx.x; // 0 .. HD*NN-1
    if (idx >= HD*NN) return;
    {   // W1: idx -> h, n
        int h = idx >> 9;          // / NN
        int n = idx & (NN - 1);
        int p = n >> 1, t = n & 1;
        W1[idx] = B_mat[(size_t)p*HD*2 + (size_t)h*2 + t];
    }
    {   // C2: idx -> n, h
        int n = idx >> 10;         // / HD
        int h = idx & (HD - 1);
        int p = n >> 1, t = n & 1;
        float sgn = (t == 0) ? 1.0f : -1.0f;
        C2[idx] = sgn * C_mat[(size_t)h*PCH*2 + (size_t)p*2 + t];
    }
}

// ---- f32 tiled GEMM: C[M x N] = A[M x K] * Bw[K x N] (+ epilogue x*D) ----
// BM=BN=128, BK=16, 256 threads, 8x8 per thread
template <bool EPI>
__global__ __launch_bounds__(256)
void gemm_f32(const float* __restrict__ A, const float* __restrict__ Bw,
              float* __restrict__ C, int K, int N,
              const float* __restrict__ xres, const float* __restrict__ Dv) {
    const int BM = 128, BN = 128, BK = 16;
    __shared__ float As[BK][BM + 4];
    __shared__ float Bs[BK][BN + 4];
    const int tid = threadIdx.x;
    const int m0 = blockIdx.y * BM;
    const int n0 = blockIdx.x * BN;
    const int tm = tid >> 4;     // 0..15
    const int tn = tid & 15;     // 0..15

    float acc[8][8];
    #pragma unroll
    for (int i = 0; i < 8; ++i)
        #pragma unroll
        for (int j = 0; j < 8; ++j) acc[i][j] = 0.0f;

    for (int k0 = 0; k0 < K; k0 += BK) {
        // A tile: 128 rows x 16 cols = 512 float4
        #pragma unroll
        for (int s = 0; s < 2; ++s) {
            int f = tid + s * 256;
            int row = f >> 2, c4 = f & 3;
            const float4 v = *(const float4*)(A + (size_t)(m0 + row) * K + k0 + c4 * 4);
            As[c4*4+0][row] = v.x;
            As[c4*4+1][row] = v.y;
            As[c4*4+2][row] = v.z;
            As[c4*4+3][row] = v.w;
        }
        // B tile: 16 rows x 128 cols = 512 float4
        #pragma unroll
        for (int s = 0; s < 2; ++s) {
            int f = tid + s * 256;
            int row = f >> 5, c4 = f & 31;
            const float4 v = *(const float4*)(Bw + (size_t)(k0 + row) * N + n0 + c4 * 4);
            *(float4*)&Bs[row][c4 * 4] = v;
        }
        __syncthreads();
        #pragma unroll
        for (int kk = 0; kk < BK; ++kk) {
            float a[8], b[8];
            *(float4*)&a[0] = *(const float4*)&As[kk][tm * 8];
            *(float4*)&a[4] = *(const float4*)&As[kk][tm * 8 + 4];
            *(float4*)&b[0] = *(const float4*)&Bs[kk][tn * 8];
            *(float4*)&b[4] = *(const float4*)&Bs[kk][tn * 8 + 4];
            #pragma unroll
            for (int i = 0; i < 8; ++i)
                #pragma unroll
                for (int j = 0; j < 8; ++j)
                    acc[i][j] = fmaf(a[i], b[j], acc[i][j]);
        }
        __syncthreads();
    }

    #pragma unroll
    for (int i = 0; i < 8; ++i) {
        size_t r = (size_t)(m0 + tm * 8 + i);
        float* cp = C + r * N + n0 + tn * 8;
        float vals[8];
        #pragma unroll
        for (int j = 0; j < 8; ++j) vals[j] = acc[i][j];
        if (EPI) {
            const float* xp = xres + r * N + n0 + tn * 8;
            #pragma unroll
            for (int j = 0; j < 8; ++j)
                vals[j] = fmaf(xp[j], Dv[n0 + tn * 8 + j], vals[j]);
        }
        *(float4*)&cp[0] = *(float4*)&vals[0];
        *(float4*)&cp[4] = *(float4*)&vals[4];
    }
}

// ---- scan phase 1: zero-init local chunk scans, store chunk-end states ----
// grid: BB*NCH blocks, 512 threads (one per n)
__global__ __launch_bounds__(512)
void scan_phase1(const float* __restrict__ Bu, const float* __restrict__ cst,
                 float* __restrict__ zend) {
    int bid = blockIdx.x;
    int b = bid / NCH, c = bid % NCH;
    int n = threadIdx.x;
    int p = n >> 1;
    float m11 = cst[0*PCH+p], m12 = cst[1*PCH+p], m21 = cst[2*PCH+p], m22 = cst[3*PCH+p];
    float c1 = cst[4*PCH+p], c2 = cst[5*PCH+p];
    float s1 = 0.f, s2 = 0.f;
    const float* bp = Bu + ((size_t)(b * LL + c * TCH)) * NN + n;
    #pragma unroll 4
    for (int i = 0; i < TCH; ++i) {
        float u = bp[(size_t)i * NN];
        float ns1 = fmaf(m11, s1, fmaf(m12, s2, c1 * u));
        float ns2 = fmaf(m21, s1, fmaf(m22, s2, c2 * u));
        s1 = ns1; s2 = ns2;
    }
    size_t base = ((size_t)(b * NCH + c) * 2) * NN + n;
    zend[base] = s1;
    zend[base + NN] = s2;
}

// ---- scan phase 2: sequential carry over chunks: carry_c = z_c + M^T * carry_{c-1} ----
// grid: BB blocks, 512 threads
__global__ __launch_bounds__(512)
void scan_phase2(const float* __restrict__ zend, const float* __restrict__ cst,
                 float* __restrict__ carry) {
    int b = blockIdx.x;
    int n = threadIdx.x;
    int p = n >> 1;
    float a = cst[6*PCH+p], bm = cst[7*PCH+p], cmt = cst[8*PCH+p], d = cst[9*PCH+p];
    float cs1 = 0.f, cs2 = 0.f;
    for (int c = 0; c < NCH; ++c) {
        size_t base = ((size_t)(b * NCH + c) * 2) * NN + n;
        float z1 = zend[base], z2 = zend[base + NN];
        float ns1 = fmaf(a, cs1, fmaf(bm, cs2, z1));
        float ns2 = fmaf(cmt, cs1, fmaf(d, cs2, z2));
        carry[base] = ns1;
        carry[base + NN] = ns2;
        cs1 = ns1; cs2 = ns2;
    }
}

// ---- scan phase 3: re-run chunks with correct init, write ys = s2 ----
__global__ __launch_bounds__(512)
void scan_phase3(const float* __restrict__ Bu, const float* __restrict__ cst,
                 const float* __restrict__ carry, float* __restrict__ ys) {
    int bid = blockIdx.x;
    int b = bid / NCH, c = bid % NCH;
    int n = threadIdx.x;
    int p = n >> 1;
    float m11 = cst[0*PCH+p], m12 = cst[1*PCH+p], m21 = cst[2*PCH+p], m22 = cst[3*PCH+p];
    float c1 = cst[4*PCH+p], c2 = cst[5*PCH+p];
    float s1 = 0.f, s2 = 0.f;
    if (c > 0) {
        size_t base = ((size_t)(b * NCH + (c - 1)) * 2) * NN + n;
        s1 = carry[base];
        s2 = carry[base + NN];
    }
    const float* bp = Bu + ((size_t)(b * LL + c * TCH)) * NN + n;
    float* yp = ys + ((size_t)(b * LL + c * TCH)) * NN + n;
    #pragma unroll 4
    for (int i = 0; i < TCH; ++i) {
        float u = bp[(size_t)i * NN];
        float ns1 = fmaf(m11, s1, fmaf(m12, s2, c1 * u));
        float ns2 = fmaf(m21, s1, fmaf(m22, s2, c2 * u));
        s1 = ns1; s2 = ns2;
        yp[(size_t)i * NN] = s2;
    }
}

extern "C" void kernel_launch(void* const* d_in, const int* in_sizes, int n_in,
                              void* d_out, int out_size, void* d_ws, size_t ws_size,
                              hipStream_t stream) {
    const float* x         = (const float*)d_in[0];
    const float* steps_raw = (const float*)d_in[1];
    const float* G_raw     = (const float*)d_in[2];
    const float* A_raw     = (const float*)d_in[3];
    const float* B_mat     = (const float*)d_in[4];
    const float* C_mat     = (const float*)d_in[5];
    const float* D_vec     = (const float*)d_in[6];
    float* out = (float*)d_out;
    float* ws  = (float*)d_ws;

    float* W1    = ws + OFF_W1;
    float* C2    = ws + OFF_C2;
    float* cst   = ws + OFF_CONSTS;
    float* Bu    = ws + OFF_BU;
    float* ys    = ws + OFF_YS;
    float* zend  = ws + OFF_ZEND;
    float* carry = ws + OFF_CARRY;

    prep_consts<<<1, 256, 0, stream>>>(steps_raw, G_raw, A_raw, cst);
    prep_w<<<(HD * NN) / 512, 512, 0, stream>>>(B_mat, C_mat, W1, C2);

    // GEMM1: Bu[32768 x 512] = x[32768 x 1024] * W1[1024 x 512]
    gemm_f32<false><<<dim3(NN / 128, MROWS / 128), 256, 0, stream>>>(
        x, W1, Bu, HD, NN, nullptr, nullptr);

    scan_phase1<<<BB * NCH, 512, 0, stream>>>(Bu, cst, zend);
    scan_phase2<<<BB, 512, 0, stream>>>(zend, cst, carry);
    scan_phase3<<<BB * NCH, 512, 0, stream>>>(Bu, cst, carry, ys);

    // GEMM2: out[32768 x 1024] = ys[32768 x 512] * C2[512 x 1024] + x * D
    gemm_f32<true><<<dim3(HD / 128, MROWS / 128), 256, 0, stream>>>(
        ys, C2, out, NN, HD, x, D_vec);
}

// Round 2
// 288.469 us; speedup vs baseline: 2.9198x; 2.9198x over previous
//
#include <hip/hip_runtime.h>
#include <math.h>
#include <stdint.h>

#define PCH 256
#define HD  1024
#define BB  8
#define LL  4096
#define NN  512                  // 2*P
#define MROWS (BB*LL)            // 32768
#define NCH 64                   // number of chunks
#define TCH 64                   // chunk length (NCH*TCH == LL)

typedef __bf16 bf16x8 __attribute__((ext_vector_type(8)));
typedef float  f32x4  __attribute__((ext_vector_type(4)));
typedef short  s16x8  __attribute__((ext_vector_type(8)));

// ---- workspace layout (byte offsets) ----
#define OFFB_XBF   ((size_t)0)                        // 32768*1024*2 = 67108864
#define OFFB_W1    (OFFB_XBF + (size_t)67108864)      // [NN][HD] bf16 = 1 MB
#define OFFB_C2    (OFFB_W1  + (size_t)1048576)       // [HD][NN] bf16 = 1 MB
#define OFFB_CST   (OFFB_C2  + (size_t)1048576)       // 16 KB
#define OFFB_BU    (OFFB_CST + (size_t)16384)         // [M][NN] f32 = 64 MB
#define OFFB_YS    (OFFB_BU  + (size_t)67108864)      // [M][NN] bf16 = 32 MB
#define OFFB_ZEND  (OFFB_YS  + (size_t)33554432)      // 2 MB
#define OFFB_CARRY (OFFB_ZEND + (size_t)2097152)      // 2 MB

__device__ __forceinline__ short f2bf(float f) {
    union { float f; uint32_t u; } v; v.f = f;
    uint32_t r = v.u + 0x7FFFu + ((v.u >> 16) & 1u);
    return (short)(r >> 16);
}

// consts layout: j*PCH + p ; j: 0=m11 1=m12 2=m21 3=m22 4=c1 5=c2 6=mt11 7=mt12 8=mt21 9=mt22
__global__ void prep_consts(const float* __restrict__ steps_raw,
                            const float* __restrict__ G_raw,
                            const float* __restrict__ A_raw,
                            float* __restrict__ cst) {
    int p = threadIdx.x;
    if (p >= PCH) return;
    float steps = 1.0f / (1.0f + expf(-steps_raw[p]));
    float G = fmaxf(G_raw[p], 0.0f);
    float A = fmaxf(A_raw[p], 0.0f);
    float S = 1.0f + steps * G;
    float alpha = steps * steps * A / S;
    alpha = 1.99f * tanhf(alpha / 1.99f);
    float m11 = 1.0f / S;
    float m12 = -alpha / steps;
    float m21 = steps / S;
    float m22 = 1.0f - alpha;
    float c1 = steps / S;
    float c2 = steps * steps / S;
    float a = 1.f, b = 0.f, c = 0.f, d = 1.f;
    for (int i = 0; i < TCH; ++i) {
        float na = m11*a + m12*c;
        float nb = m11*b + m12*d;
        float nc = m21*a + m22*c;
        float nd = m21*b + m22*d;
        a = na; b = nb; c = nc; d = nd;
    }
    cst[0*PCH+p] = m11; cst[1*PCH+p] = m12; cst[2*PCH+p] = m21; cst[3*PCH+p] = m22;
    cst[4*PCH+p] = c1;  cst[5*PCH+p] = c2;
    cst[6*PCH+p] = a;   cst[7*PCH+p] = b;   cst[8*PCH+p] = c;   cst[9*PCH+p] = d;
}

// W1t[n][h] = bf16(B_mat[p][h][t]); C2t[h][n] = bf16(sign(t)*C_mat[h][p][t]); n=2p+t
__global__ void prep_w(const float* __restrict__ B_mat,
                       const float* __restrict__ C_mat,
                       short* __restrict__ W1t,
                       short* __restrict__ C2t) {
    int idx = blockIdx.x * blockDim.x + threadIdx.x; // 0 .. 524287
    if (idx >= HD * NN) return;
    {   // W1t is [NN][HD]
        int n = idx >> 10;
        int h = idx & (HD - 1);
        int p = n >> 1, t = n & 1;
        W1t[idx] = f2bf(B_mat[(size_t)p * HD * 2 + (size_t)h * 2 + t]);
    }
    {   // C2t is [HD][NN]
        int h = idx >> 9;
        int n = idx & (NN - 1);
        int p = n >> 1, t = n & 1;
        float sgn = (t == 0) ? 1.0f : -1.0f;
        C2t[idx] = f2bf(sgn * C_mat[(size_t)h * PCH * 2 + (size_t)p * 2 + t]);
    }
}

// x f32 -> bf16, vectorized 8/thread, grid-stride
__global__ __launch_bounds__(256) void cvt_bf16(const float* __restrict__ in,
                                                short* __restrict__ out, int n8) {
    int i = blockIdx.x * blockDim.x + threadIdx.x;
    int stride = gridDim.x * blockDim.x;
    for (; i < n8; i += stride) {
        float4 a = ((const float4*)in)[2 * i];
        float4 b = ((const float4*)in)[2 * i + 1];
        s16x8 r;
        r[0] = f2bf(a.x); r[1] = f2bf(a.y); r[2] = f2bf(a.z); r[3] = f2bf(a.w);
        r[4] = f2bf(b.x); r[5] = f2bf(b.y); r[6] = f2bf(b.z); r[7] = f2bf(b.w);
        ((s16x8*)out)[i] = r;
    }
}

// ---- bf16 MFMA GEMM: C[M x N](f32) = A[M x K](bf16) * Bt[N x K](bf16)^T ----
// 128x128 tile, BK=32, 256 threads (4 waves, 2x2), 4x4 16x16x32 frags per wave.
// LDS: double-buffered; tiles stored [row][k] 64B rows with 16B-chunk XOR swizzle
// (slot = q ^ ((row>>1)&3)); global source pre-swizzled, ds_read swizzled.
template <int K, int N, bool EPI>
__global__ __launch_bounds__(256)
void gemm_bf16(const short* __restrict__ A, const short* __restrict__ Bt,
               float* __restrict__ C,
               const float* __restrict__ xres, const float* __restrict__ Dv) {
    __shared__ alignas(16) char smem[32768];  // 2 bufs x (A 8KB + B 8KB)
    const int tid = threadIdx.x;
    const int m0 = blockIdx.y * 128;
    const int n0 = blockIdx.x * 128;
    const int lane = tid & 63;
    const int w = tid >> 6;
    const int wm = w >> 1, wn = w & 1;
    const int g = lane >> 4, r16 = lane & 15;

    // fragment read offsets (swizzled)
    int aoff[4], boff[4];
    #pragma unroll
    for (int i = 0; i < 4; ++i) {
        int ra = wm * 64 + i * 16 + r16;
        aoff[i] = ra * 64 + ((g ^ ((ra >> 1) & 3)) << 4);
        int rb = wn * 64 + i * 16 + r16;
        boff[i] = 8192 + rb * 64 + ((g ^ ((rb >> 1) & 3)) << 4);
    }

    f32x4 acc[4][4];
    #pragma unroll
    for (int i = 0; i < 4; ++i)
        #pragma unroll
        for (int j = 0; j < 4; ++j) acc[i][j] = (f32x4)0.0f;

    auto stage = [&](int buf, int k0) {
        #pragma unroll
        for (int s = 0; s < 2; ++s) {
            int c = tid + s * 256;
            int row = c >> 2, q = c & 3;
            int gq = q ^ ((row >> 1) & 3);
            const short* sa = A + (size_t)(m0 + row) * K + k0 + gq * 8;
            __builtin_amdgcn_global_load_lds(
                (const __attribute__((address_space(1))) void*)sa,
                (__attribute__((address_space(3))) void*)(smem + buf * 16384 + c * 16),
                16, 0, 0);
            const short* sb = Bt + (size_t)(n0 + row) * K + k0 + gq * 8;
            __builtin_amdgcn_global_load_lds(
                (const __attribute__((address_space(1))) void*)sb,
                (__attribute__((address_space(3))) void*)(smem + buf * 16384 + 8192 + c * 16),
                16, 0, 0);
        }
    };

    const int NT = K / 32;
    stage(0, 0);
    int cur = 0;
    for (int t = 0; t < NT; ++t) {
        __syncthreads();  // drains vmcnt -> buf[cur] ready; protects buf[cur^1] reuse
        if (t + 1 < NT) stage(cur ^ 1, (t + 1) * 32);
        const char* base = smem + cur * 16384;
        bf16x8 af[4], bfv[4];
        #pragma unroll
        for (int i = 0; i < 4; ++i) af[i] = *(const bf16x8*)(base + aoff[i]);
        #pragma unroll
        for (int j = 0; j < 4; ++j) bfv[j] = *(const bf16x8*)(base + boff[j]);
        #pragma unroll
        for (int i = 0; i < 4; ++i)
            #pragma unroll
            for (int j = 0; j < 4; ++j)
                acc[i][j] = __builtin_amdgcn_mfma_f32_16x16x32_bf16(af[i], bfv[j], acc[i][j], 0, 0, 0);
        cur ^= 1;
    }

    // epilogue: C/D map col=lane&15, row=(lane>>4)*4+reg
    const int crow0 = m0 + wm * 64 + g * 4;
    const int ccol0 = n0 + wn * 64 + r16;
    #pragma unroll
    for (int j = 0; j < 4; ++j) {
        int col = ccol0 + j * 16;
        float dv = EPI ? Dv[col] : 0.0f;
        #pragma unroll
        for (int i = 0; i < 4; ++i) {
            #pragma unroll
            for (int r = 0; r < 4; ++r) {
                size_t idx = (size_t)(crow0 + i * 16 + r) * N + col;
                float v = acc[i][j][r];
                if (EPI) v = fmaf(xres[idx], dv, v);
                C[idx] = v;
            }
        }
    }
}

// ---- scan phase 1: zero-init local chunk scans, store chunk-end states ----
__global__ __launch_bounds__(512)
void scan_phase1(const float* __restrict__ Bu, const float* __restrict__ cst,
                 float* __restrict__ zend) {
    int bid = blockIdx.x;
    int b = bid / NCH, c = bid % NCH;
    int n = threadIdx.x;
    int p = n >> 1;
    float m11 = cst[0*PCH+p], m12 = cst[1*PCH+p], m21 = cst[2*PCH+p], m22 = cst[3*PCH+p];
    float c1 = cst[4*PCH+p], c2 = cst[5*PCH+p];
    float s1 = 0.f, s2 = 0.f;
    const float* bp = Bu + ((size_t)(b * LL + c * TCH)) * NN + n;
    #pragma unroll 4
    for (int i = 0; i < TCH; ++i) {
        float u = bp[(size_t)i * NN];
        float ns1 = fmaf(m11, s1, fmaf(m12, s2, c1 * u));
        float ns2 = fmaf(m21, s1, fmaf(m22, s2, c2 * u));
        s1 = ns1; s2 = ns2;
    }
    size_t base = ((size_t)(b * NCH + c) * 2) * NN + n;
    zend[base] = s1;
    zend[base + NN] = s2;
}

// ---- scan phase 2: carry_c = z_c + M^TCH * carry_{c-1} ----
__global__ __launch_bounds__(512)
void scan_phase2(const float* __restrict__ zend, const float* __restrict__ cst,
                 float* __restrict__ carry) {
    int b = blockIdx.x;
    int n = threadIdx.x;
    int p = n >> 1;
    float a = cst[6*PCH+p], bm = cst[7*PCH+p], cmt = cst[8*PCH+p], d = cst[9*PCH+p];
    float cs1 = 0.f, cs2 = 0.f;
    for (int c = 0; c < NCH; ++c) {
        size_t base = ((size_t)(b * NCH + c) * 2) * NN + n;
        float z1 = zend[base], z2 = zend[base + NN];
        float ns1 = fmaf(a, cs1, fmaf(bm, cs2, z1));
        float ns2 = fmaf(cmt, cs1, fmaf(d, cs2, z2));
        carry[base] = ns1;
        carry[base + NN] = ns2;
        cs1 = ns1; cs2 = ns2;
    }
}

// ---- scan phase 3: re-run chunks with correct init, write ys = s2 as bf16 ----
__global__ __launch_bounds__(512)
void scan_phase3(const float* __restrict__ Bu, const float* __restrict__ cst,
                 const float* __restrict__ carry, short* __restrict__ ys) {
    int bid = blockIdx.x;
    int b = bid / NCH, c = bid % NCH;
    int n = threadIdx.x;
    int p = n >> 1;
    float m11 = cst[0*PCH+p], m12 = cst[1*PCH+p], m21 = cst[2*PCH+p], m22 = cst[3*PCH+p];
    float c1 = cst[4*PCH+p], c2 = cst[5*PCH+p];
    float s1 = 0.f, s2 = 0.f;
    if (c > 0) {
        size_t base = ((size_t)(b * NCH + (c - 1)) * 2) * NN + n;
        s1 = carry[base];
        s2 = carry[base + NN];
    }
    const float* bp = Bu + ((size_t)(b * LL + c * TCH)) * NN + n;
    short* yp = ys + ((size_t)(b * LL + c * TCH)) * NN + n;
    #pragma unroll 4
    for (int i = 0; i < TCH; ++i) {
        float u = bp[(size_t)i * NN];
        float ns1 = fmaf(m11, s1, fmaf(m12, s2, c1 * u));
        float ns2 = fmaf(m21, s1, fmaf(m22, s2, c2 * u));
        s1 = ns1; s2 = ns2;
        yp[(size_t)i * NN] = f2bf(s2);
    }
}

extern "C" void kernel_launch(void* const* d_in, const int* in_sizes, int n_in,
                              void* d_out, int out_size, void* d_ws, size_t ws_size,
                              hipStream_t stream) {
    const float* x         = (const float*)d_in[0];
    const float* steps_raw = (const float*)d_in[1];
    const float* G_raw     = (const float*)d_in[2];
    const float* A_raw     = (const float*)d_in[3];
    const float* B_mat     = (const float*)d_in[4];
    const float* C_mat     = (const float*)d_in[5];
    const float* D_vec     = (const float*)d_in[6];
    float* out = (float*)d_out;
    char*  ws  = (char*)d_ws;

    short* xbf   = (short*)(ws + OFFB_XBF);
    short* W1t   = (short*)(ws + OFFB_W1);
    short* C2t   = (short*)(ws + OFFB_C2);
    float* cst   = (float*)(ws + OFFB_CST);
    float* Bu    = (float*)(ws + OFFB_BU);
    short* ysbf  = (short*)(ws + OFFB_YS);
    float* zend  = (float*)(ws + OFFB_ZEND);
    float* carry = (float*)(ws + OFFB_CARRY);

    prep_consts<<<1, 256, 0, stream>>>(steps_raw, G_raw, A_raw, cst);
    prep_w<<<(HD * NN) / 512, 512, 0, stream>>>(B_mat, C_mat, W1t, C2t);
    cvt_bf16<<<2048, 256, 0, stream>>>(x, xbf, (MROWS * HD) / 8);

    // GEMM1: Bu[32768 x 512] = xbf * W1t^T
    gemm_bf16<HD, NN, false><<<dim3(NN / 128, MROWS / 128), 256, 0, stream>>>(
        xbf, W1t, Bu, nullptr, nullptr);

    scan_phase1<<<BB * NCH, 512, 0, stream>>>(Bu, cst, zend);
    scan_phase2<<<BB, 512, 0, stream>>>(zend, cst, carry);
    scan_phase3<<<BB * NCH, 512, 0, stream>>>(Bu, cst, carry, ysbf);

    // GEMM2: out[32768 x 1024] = ysbf * C2t^T + x*D
    gemm_bf16<NN, HD, true><<<dim3(HD / 128, MROWS / 128), 256, 0, stream>>>(
        ysbf, C2t, out, x, D_vec);
}

// Round 3
// 198.566 us; speedup vs baseline: 4.2418x; 1.4528x over previous
//
#include <hip/hip_runtime.h>
#include <math.h>
#include <stdint.h>

#define PCH 256
#define HD  1024
#define BB  8
#define LL  4096
#define NN  512                  // 2*P
#define MROWS (BB*LL)            // 32768
#define NCH 64                   // number of chunks
#define TCH 64                   // chunk length (NCH*TCH == LL)

typedef __bf16 bf16x8 __attribute__((ext_vector_type(8)));
typedef float  f32x4  __attribute__((ext_vector_type(4)));
typedef short  s16x8  __attribute__((ext_vector_type(8)));

// ---- workspace layout (byte offsets) ----
#define OFFB_XBF   ((size_t)0)                          // 32768*1024*2 = 64 MB
#define OFFB_W1    (OFFB_XBF + (size_t)MROWS*HD*2)      // [NN][HD] bf16 = 1 MB
#define OFFB_C2    (OFFB_W1  + (size_t)NN*HD*2)         // [HD][NN] bf16 = 1 MB
#define OFFB_CST   (OFFB_C2  + (size_t)HD*NN*2)         // 16 KB
#define OFFB_BU    (OFFB_CST + (size_t)16384)           // [M][NN] bf16 = 32 MB
#define OFFB_YS    (OFFB_BU  + (size_t)MROWS*NN*2)      // [M][NN] bf16 = 32 MB
#define OFFB_ZEND  (OFFB_YS  + (size_t)MROWS*NN*2)      // 2 MB
#define OFFB_CARRY (OFFB_ZEND + (size_t)BB*NCH*2*NN*4)  // 2 MB

__device__ __forceinline__ short f2bf(float f) {
    union { float f; uint32_t u; } v; v.f = f;
    uint32_t r = v.u + 0x7FFFu + ((v.u >> 16) & 1u);
    return (short)(r >> 16);
}
__device__ __forceinline__ float bf2f(unsigned short u) {
    union { uint32_t u; float f; } v; v.u = ((uint32_t)u) << 16;
    return v.f;
}

// consts layout: j*PCH + p ; j: 0=m11 1=m12 2=m21 3=m22 4=c1 5=c2 6=mt11 7=mt12 8=mt21 9=mt22
__global__ void prep_consts(const float* __restrict__ steps_raw,
                            const float* __restrict__ G_raw,
                            const float* __restrict__ A_raw,
                            float* __restrict__ cst) {
    int p = threadIdx.x;
    if (p >= PCH) return;
    float steps = 1.0f / (1.0f + expf(-steps_raw[p]));
    float G = fmaxf(G_raw[p], 0.0f);
    float A = fmaxf(A_raw[p], 0.0f);
    float S = 1.0f + steps * G;
    float alpha = steps * steps * A / S;
    alpha = 1.99f * tanhf(alpha / 1.99f);
    float m11 = 1.0f / S;
    float m12 = -alpha / steps;
    float m21 = steps / S;
    float m22 = 1.0f - alpha;
    float c1 = steps / S;
    float c2 = steps * steps / S;
    float a = 1.f, b = 0.f, c = 0.f, d = 1.f;
    for (int i = 0; i < TCH; ++i) {
        float na = m11*a + m12*c;
        float nb = m11*b + m12*d;
        float nc = m21*a + m22*c;
        float nd = m21*b + m22*d;
        a = na; b = nb; c = nc; d = nd;
    }
    cst[0*PCH+p] = m11; cst[1*PCH+p] = m12; cst[2*PCH+p] = m21; cst[3*PCH+p] = m22;
    cst[4*PCH+p] = c1;  cst[5*PCH+p] = c2;
    cst[6*PCH+p] = a;   cst[7*PCH+p] = b;   cst[8*PCH+p] = c;   cst[9*PCH+p] = d;
}

// W1t[n][h] = bf16(B_mat[p][h][t]); C2t[h][n] = bf16(sign(t)*C_mat[h][p][t]); n=2p+t
__global__ void prep_w(const float* __restrict__ B_mat,
                       const float* __restrict__ C_mat,
                       short* __restrict__ W1t,
                       short* __restrict__ C2t) {
    int idx = blockIdx.x * blockDim.x + threadIdx.x;
    if (idx >= HD * NN) return;
    {   // W1t is [NN][HD]
        int n = idx >> 10;
        int h = idx & (HD - 1);
        int p = n >> 1, t = n & 1;
        W1t[idx] = f2bf(B_mat[(size_t)p * HD * 2 + (size_t)h * 2 + t]);
    }
    {   // C2t is [HD][NN]
        int h = idx >> 9;
        int n = idx & (NN - 1);
        int p = n >> 1, t = n & 1;
        float sgn = (t == 0) ? 1.0f : -1.0f;
        C2t[idx] = f2bf(sgn * C_mat[(size_t)h * PCH * 2 + (size_t)p * 2 + t]);
    }
}

// x f32 -> bf16, vectorized 8/thread, grid-stride
__global__ __launch_bounds__(256) void cvt_bf16(const float* __restrict__ in,
                                                short* __restrict__ out, int n8) {
    int i = blockIdx.x * blockDim.x + threadIdx.x;
    int stride = gridDim.x * blockDim.x;
    for (; i < n8; i += stride) {
        float4 a = ((const float4*)in)[2 * i];
        float4 b = ((const float4*)in)[2 * i + 1];
        s16x8 r;
        r[0] = f2bf(a.x); r[1] = f2bf(a.y); r[2] = f2bf(a.z); r[3] = f2bf(a.w);
        r[4] = f2bf(b.x); r[5] = f2bf(b.y); r[6] = f2bf(b.z); r[7] = f2bf(b.w);
        ((s16x8*)out)[i] = r;
    }
}

// ---- 256x256 bf16 MFMA GEMM, BK=64, 8 waves (2Mx4N), 2-phase dbuf ----
// C[M x N] = A[M x K](bf16) * Bt[N x K](bf16)^T ; out f32 or bf16; optional
// epilogue += bf2f(xbf)*Dv.  LDS 128KB: 2 bufs x (A 32KB + B 32KB).
// Rows are 128B (8 x 16B chunks); swizzle: chunk' = chunk ^ (row&7), applied
// on the pre-swizzled global source (linear global_load_lds dest) and on the
// ds_read address (involution, rule #21).
template <int K, int N, bool OUT_BF16, bool EPI>
__global__ __launch_bounds__(512, 2)
void gemm256(const short* __restrict__ A, const short* __restrict__ Bt,
             void* __restrict__ Cout, const short* __restrict__ xbf,
             const float* __restrict__ Dv) {
    __shared__ alignas(16) char smem[131072];
    constexpr int GX = N / 256;
    // T1: bijective XCD swizzle (gridDim.x % 8 == 0)
    const int nwg = gridDim.x;
    const int cpx = nwg >> 3;
    const int bid = blockIdx.x;
    const int wg = (bid & 7) * cpx + (bid >> 3);
    const int by = wg / GX, bx = wg % GX;
    const int m0 = by * 256, n0 = bx * 256;

    const int tid = threadIdx.x;
    const int lane = tid & 63, w = tid >> 6;
    const int wm = w >> 2, wn = w & 3;            // 2 x 4 wave grid
    const int g = lane >> 4, r16 = lane & 15;

    auto stage = [&](int buf, int k0) {
        #pragma unroll
        for (int s = 0; s < 4; ++s) {
            int c = tid + s * 512;                 // 0..2047 (256 rows x 8 chunks)
            int row = c >> 3, q = c & 7;
            int gq = q ^ (row & 7);
            const short* sa = A + (size_t)(m0 + row) * K + k0 + gq * 8;
            __builtin_amdgcn_global_load_lds(
                (const __attribute__((address_space(1))) void*)sa,
                (__attribute__((address_space(3))) void*)(smem + buf * 65536 + c * 16),
                16, 0, 0);
        }
        #pragma unroll
        for (int s = 0; s < 4; ++s) {
            int c = tid + s * 512;
            int row = c >> 3, q = c & 7;
            int gq = q ^ (row & 7);
            const short* sb = Bt + (size_t)(n0 + row) * K + k0 + gq * 8;
            __builtin_amdgcn_global_load_lds(
                (const __attribute__((address_space(1))) void*)sb,
                (__attribute__((address_space(3))) void*)(smem + buf * 65536 + 32768 + c * 16),
                16, 0, 0);
        }
    };

    // fragment read offsets for kk=0; kk=1 address = kk=0 address ^ 64
    int aoff[8], boff[4];
    #pragma unroll
    for (int mi = 0; mi < 8; ++mi) {
        int ra = wm * 128 + mi * 16 + r16;
        aoff[mi] = ra * 128 + ((g ^ (ra & 7)) << 4);
    }
    #pragma unroll
    for (int nj = 0; nj < 4; ++nj) {
        int rb = wn * 64 + nj * 16 + r16;
        boff[nj] = 32768 + rb * 128 + ((g ^ (rb & 7)) << 4);
    }

    f32x4 acc[8][4];
    #pragma unroll
    for (int mi = 0; mi < 8; ++mi)
        #pragma unroll
        for (int nj = 0; nj < 4; ++nj) acc[mi][nj] = (f32x4)0.0f;

    constexpr int NT = K / 64;
    stage(0, 0);
    __syncthreads();                 // vmcnt(0)+barrier: buf0 ready
    int cur = 0;
    #pragma unroll 1
    for (int t = 0; t < NT; ++t) {
        if (t + 1 < NT) stage(cur ^ 1, (t + 1) * 64);   // loads in flight during MFMA
        const char* base = smem + cur * 65536;
        #pragma unroll
        for (int kk = 0; kk < 2; ++kk) {
            bf16x8 af[8], bfv[4];
            #pragma unroll
            for (int mi = 0; mi < 8; ++mi)
                af[mi] = *(const bf16x8*)(base + (aoff[mi] ^ (kk << 6)));
            #pragma unroll
            for (int nj = 0; nj < 4; ++nj)
                bfv[nj] = *(const bf16x8*)(base + (boff[nj] ^ (kk << 6)));
            #pragma unroll
            for (int mi = 0; mi < 8; ++mi)
                #pragma unroll
                for (int nj = 0; nj < 4; ++nj)
                    acc[mi][nj] = __builtin_amdgcn_mfma_f32_16x16x32_bf16(
                        af[mi], bfv[nj], acc[mi][nj], 0, 0, 0);
        }
        __syncthreads();             // drains vmcnt(0): next buf landed; LDS reads done
        cur ^= 1;
    }

    // epilogue: C/D map col=lane&15, row=(lane>>4)*4+reg
    const int crow0 = m0 + wm * 128 + g * 4;
    const int ccol0 = n0 + wn * 64 + r16;
    #pragma unroll
    for (int nj = 0; nj < 4; ++nj) {
        int col = ccol0 + nj * 16;
        float dv = EPI ? Dv[col] : 0.0f;
        #pragma unroll
        for (int mi = 0; mi < 8; ++mi) {
            #pragma unroll
            for (int r = 0; r < 4; ++r) {
                size_t idx = (size_t)(crow0 + mi * 16 + r) * N + col;
                float v = acc[mi][nj][r];
                if (EPI) v = fmaf(bf2f(((const unsigned short*)xbf)[idx]), dv, v);
                if (OUT_BF16) ((unsigned short*)Cout)[idx] = (unsigned short)f2bf(v);
                else          ((float*)Cout)[idx] = v;
            }
        }
    }
}

// ---- scan phase 1: zero-init local chunk scans over bf16 Bu ----
__global__ __launch_bounds__(512)
void scan_phase1(const unsigned short* __restrict__ Bu, const float* __restrict__ cst,
                 float* __restrict__ zend) {
    int bid = blockIdx.x;
    int b = bid / NCH, c = bid % NCH;
    int n = threadIdx.x;
    int p = n >> 1;
    float m11 = cst[0*PCH+p], m12 = cst[1*PCH+p], m21 = cst[2*PCH+p], m22 = cst[3*PCH+p];
    float c1 = cst[4*PCH+p], c2 = cst[5*PCH+p];
    float s1 = 0.f, s2 = 0.f;
    const unsigned short* bp = Bu + ((size_t)(b * LL + c * TCH)) * NN + n;
    #pragma unroll 4
    for (int i = 0; i < TCH; ++i) {
        float u = bf2f(bp[(size_t)i * NN]);
        float ns1 = fmaf(m11, s1, fmaf(m12, s2, c1 * u));
        float ns2 = fmaf(m21, s1, fmaf(m22, s2, c2 * u));
        s1 = ns1; s2 = ns2;
    }
    size_t base = ((size_t)(b * NCH + c) * 2) * NN + n;
    zend[base] = s1;
    zend[base + NN] = s2;
}

// ---- scan phase 2: carry_c = z_c + M^TCH * carry_{c-1} ----
__global__ __launch_bounds__(512)
void scan_phase2(const float* __restrict__ zend, const float* __restrict__ cst,
                 float* __restrict__ carry) {
    int b = blockIdx.x;
    int n = threadIdx.x;
    int p = n >> 1;
    float a = cst[6*PCH+p], bm = cst[7*PCH+p], cmt = cst[8*PCH+p], d = cst[9*PCH+p];
    float cs1 = 0.f, cs2 = 0.f;
    for (int c = 0; c < NCH; ++c) {
        size_t base = ((size_t)(b * NCH + c) * 2) * NN + n;
        float z1 = zend[base], z2 = zend[base + NN];
        float ns1 = fmaf(a, cs1, fmaf(bm, cs2, z1));
        float ns2 = fmaf(cmt, cs1, fmaf(d, cs2, z2));
        carry[base] = ns1;
        carry[base + NN] = ns2;
        cs1 = ns1; cs2 = ns2;
    }
}

// ---- scan phase 3: re-run chunks with correct init, write ys = s2 as bf16 ----
__global__ __launch_bounds__(512)
void scan_phase3(const unsigned short* __restrict__ Bu, const float* __restrict__ cst,
                 const float* __restrict__ carry, unsigned short* __restrict__ ys) {
    int bid = blockIdx.x;
    int b = bid / NCH, c = bid % NCH;
    int n = threadIdx.x;
    int p = n >> 1;
    float m11 = cst[0*PCH+p], m12 = cst[1*PCH+p], m21 = cst[2*PCH+p], m22 = cst[3*PCH+p];
    float c1 = cst[4*PCH+p], c2 = cst[5*PCH+p];
    float s1 = 0.f, s2 = 0.f;
    if (c > 0) {
        size_t base = ((size_t)(b * NCH + (c - 1)) * 2) * NN + n;
        s1 = carry[base];
        s2 = carry[base + NN];
    }
    const unsigned short* bp = Bu + ((size_t)(b * LL + c * TCH)) * NN + n;
    unsigned short* yp = ys + ((size_t)(b * LL + c * TCH)) * NN + n;
    #pragma unroll 4
    for (int i = 0; i < TCH; ++i) {
        float u = bf2f(bp[(size_t)i * NN]);
        float ns1 = fmaf(m11, s1, fmaf(m12, s2, c1 * u));
        float ns2 = fmaf(m21, s1, fmaf(m22, s2, c2 * u));
        s1 = ns1; s2 = ns2;
        yp[(size_t)i * NN] = (unsigned short)f2bf(s2);
    }
}

extern "C" void kernel_launch(void* const* d_in, const int* in_sizes, int n_in,
                              void* d_out, int out_size, void* d_ws, size_t ws_size,
                              hipStream_t stream) {
    const float* x         = (const float*)d_in[0];
    const float* steps_raw = (const float*)d_in[1];
    const float* G_raw     = (const float*)d_in[2];
    const float* A_raw     = (const float*)d_in[3];
    const float* B_mat     = (const float*)d_in[4];
    const float* C_mat     = (const float*)d_in[5];
    const float* D_vec     = (const float*)d_in[6];
    float* out = (float*)d_out;
    char*  ws  = (char*)d_ws;

    short*          xbf   = (short*)(ws + OFFB_XBF);
    short*          W1t   = (short*)(ws + OFFB_W1);
    short*          C2t   = (short*)(ws + OFFB_C2);
    float*          cst   = (float*)(ws + OFFB_CST);
    unsigned short* Bu    = (unsigned short*)(ws + OFFB_BU);
    unsigned short* ysbf  = (unsigned short*)(ws + OFFB_YS);
    float*          zend  = (float*)(ws + OFFB_ZEND);
    float*          carry = (float*)(ws + OFFB_CARRY);

    prep_consts<<<1, 256, 0, stream>>>(steps_raw, G_raw, A_raw, cst);
    prep_w<<<(HD * NN) / 512, 512, 0, stream>>>(B_mat, C_mat, W1t, C2t);
    cvt_bf16<<<2048, 256, 0, stream>>>(x, xbf, (MROWS * HD) / 8);

    // GEMM1: Bu[32768 x 512](bf16) = xbf * W1t^T   (grid 2x128 = 256 blocks)
    gemm256<HD, NN, true, false><<<(NN / 256) * (MROWS / 256), 512, 0, stream>>>(
        xbf, W1t, (void*)Bu, nullptr, nullptr);

    scan_phase1<<<BB * NCH, 512, 0, stream>>>(Bu, cst, zend);
    scan_phase2<<<BB, 512, 0, stream>>>(zend, cst, carry);
    scan_phase3<<<BB * NCH, 512, 0, stream>>>(Bu, cst, carry, ysbf);

    // GEMM2: out[32768 x 1024](f32) = ysbf * C2t^T + bf2f(xbf)*D  (grid 4x128 = 512 blocks)
    gemm256<NN, HD, false, true><<<(HD / 256) * (MROWS / 256), 512, 0, stream>>>(
        (const short*)ysbf, C2t, (void*)out, xbf, D_vec);
}